// Round 3
// baseline (246.513 us; speedup 1.0000x reference)
//
#include <hip/hip_runtime.h>
#include <cfloat>
#include <cmath>

#define DIM 64
#define TT 2048
#define NTOT 65536
#define KE 1024

// Block = 64 t-values x full K, 4 waves = 4-way K-split (256 codes each).
// Inner loop: e-row via SCALAR loads (uniform address -> s_load, SGPR operand
// in v_fma is free), x held in 64 VGPRs, zero LDS traffic in the hot loop.
__global__ __launch_bounds__(256) void argmin_kernel(
    const float* __restrict__ x,       // [B][D][T]
    const float* __restrict__ embed,   // [K][D] row-major (contiguous rows!)
    float* __restrict__ out_q,         // [B][D][T]
    float* __restrict__ out_idx,       // [B][T] (as float)
    float* __restrict__ counts,        // = out_avg region, pre-zeroed
    float* __restrict__ distsum)       // = out_commit slot, pre-zeroed
{
    __shared__ float e2s[KE];          // ||e_c||^2
    __shared__ float rbs[4][64];       // per-wave best dist
    __shared__ int   rbi[4][64];       // per-wave best idx
    __shared__ int   ibest[64];        // combined best idx per t
    __shared__ float mdsum[1];

    const int tid  = threadIdx.x;
    const int lane = tid & 63;
    // force wave id into an SGPR so code addresses are provably wave-uniform
    const int w    = __builtin_amdgcn_readfirstlane(tid >> 6);
    const int bid  = blockIdx.x;
    const int b    = bid >> 5;
    const int t0   = (bid & 31) << 6;
    const int t    = t0 + lane;

    // ---- e2 precompute (cooperative; rows cached in L2/L3 across blocks) ----
    #pragma unroll
    for (int q = 0; q < 4; ++q) {
        const int r = tid + q * 256;
        const float4* rp = (const float4*)(embed + (size_t)r * DIM);
        float s = 0.f;
        #pragma unroll
        for (int i = 0; i < 16; ++i) {
            const float4 v = rp[i];
            s += v.x * v.x + v.y * v.y + v.z * v.z + v.w * v.w;
        }
        e2s[r] = s;
    }

    // ---- load x column into registers (coalesced per j across lanes) ----
    float xr[DIM];
    float x2 = 0.f;
    #pragma unroll
    for (int j = 0; j < DIM; ++j) {
        xr[j] = x[(size_t)(b * DIM + j) * TT + t];
        x2 += xr[j] * xr[j];
    }
    __syncthreads();                   // e2s ready

    // ---- main loop: wave w handles codes [w*256, (w+1)*256) ----
    float bs = FLT_MAX;
    int   bi = 0;
    const int cbase = w << 8;          // SGPR
    for (int i = 0; i < 256; ++i) {
        const int c = cbase + i;       // uniform -> scalar loads below
        const float4* e = (const float4*)(embed + (size_t)c * DIM);
        float a0 = 0.f, a1 = 0.f, a2 = 0.f, a3 = 0.f;
        #pragma unroll
        for (int i4 = 0; i4 < 16; ++i4) {
            const float4 ev = e[i4];   // s_load_dwordx4/x16 (uniform)
            a0 = fmaf(xr[i4 * 4 + 0], ev.x, a0);
            a1 = fmaf(xr[i4 * 4 + 1], ev.y, a1);
            a2 = fmaf(xr[i4 * 4 + 2], ev.z, a2);
            a3 = fmaf(xr[i4 * 4 + 3], ev.w, a3);
        }
        const float s = fmaf(-2.f, (a0 + a1) + (a2 + a3), e2s[c]);
        // strict < + ascending c keeps lowest index on ties (numpy argmin)
        if (s < bs) { bs = s; bi = c; }
    }

    rbs[w][lane] = bs;
    rbi[w][lane] = bi;
    __syncthreads();

    // ---- wave 0: combine 4 K-quarters, write idx, counts, distsum ----
    if (tid < 64) {
        float cs = rbs[0][lane]; int ci = rbi[0][lane];
        #pragma unroll
        for (int q = 1; q < 4; ++q) {
            const float s2 = rbs[q][lane];
            if (s2 < cs) { cs = s2; ci = rbi[q][lane]; }  // quarters ascending in c
        }
        ibest[lane] = ci;
        out_idx[b * TT + t0 + lane] = (float)ci;
        atomicAdd(&counts[ci], 1.0f);
        float md = x2 + cs;            // ||x - e_best||^2
        #pragma unroll
        for (int off = 32; off > 0; off >>= 1) md += __shfl_down(md, off);
        if (lane == 0) mdsum[0] = md;
    }
    __syncthreads();
    if (tid == 0) atomicAdd(distsum, mdsum[0]);

    // ---- quantized gather: wave w writes j in [w*16, w*16+16) ----
    #pragma unroll
    for (int jj = 0; jj < 16; ++jj) {
        const int j = (w << 4) + jj;
        out_q[(size_t)(b * DIM + j) * TT + t0 + lane] =
            embed[(size_t)ibest[lane] * DIM + j];   // L1/L2-hot gather
    }
}

// finalize: in-place counts->avg_probs, perplexity, usage, commitment
__global__ __launch_bounds__(1024) void finalize_kernel(
    float* __restrict__ avg,           // in: counts, out: probs
    float* __restrict__ commit_slot,   // in: distsum, out: commitment loss
    float* __restrict__ out_perp,
    float* __restrict__ out_usage)
{
    __shared__ float s_ent[1024];
    __shared__ float s_use[1024];
    const int k = threadIdx.x;
    const float p = avg[k] * (1.0f / (float)NTOT);
    avg[k] = p;
    s_ent[k] = p * logf(p + 1e-10f);
    s_use[k] = p * logf(p * 1024.f + 1e-10f);
    __syncthreads();
    for (int off = 512; off > 0; off >>= 1) {
        if (k < off) { s_ent[k] += s_ent[k + off]; s_use[k] += s_use[k + off]; }
        __syncthreads();
    }
    if (k == 0) {
        const float ds = commit_slot[0];
        *out_perp      = expf(-s_ent[0]);
        *out_usage     = s_use[0];
        commit_slot[0] = 0.25f * ds * (1.0f / ((float)NTOT * (float)DIM));
    }
}

extern "C" void kernel_launch(void* const* d_in, const int* in_sizes, int n_in,
                              void* d_out, int out_size, void* d_ws, size_t ws_size,
                              hipStream_t stream) {
    const float* x     = (const float*)d_in[0];
    const float* embed = (const float*)d_in[1];

    float* out        = (float*)d_out;
    float* out_q      = out;             // 4194304
    float* out_commit = out + 4194304;   // 1   (distsum accumulator first)
    float* out_perp   = out + 4194305;   // 1
    float* out_avg    = out + 4194306;   // 1024 (counts accumulator first)
    float* out_idx    = out + 4195330;   // 65536
    // usage at out + 4260866

    hipMemsetAsync(out_commit, 0, 1026 * sizeof(float), stream);
    argmin_kernel<<<1024, 256, 0, stream>>>(x, embed, out_q, out_idx, out_avg, out_commit);
    finalize_kernel<<<1, 1024, 0, stream>>>(out_avg, out_commit, out_perp, out + 4260866);
}

// Round 4
// 244.273 us; speedup vs baseline: 1.0092x; 1.0092x over previous
//
#include <hip/hip_runtime.h>
#include <cfloat>
#include <cmath>

#define DIM 64
#define TT 2048
#define NTOT 65536
#define KE 1024
#define LDW 132          // LDS row stride (floats): mult of 4 (16B align), %32=4 rotation

// Block = 128 t-values x full K. 256 threads as 16(t) x 16(k), 8x8 micro-tile.
// K processed in 8 chunks of 128 codes staged to LDS.
// Hot loop: 4 ds_read_b128 (2 conflict-free x reads + 2 broadcast e reads)
// per 64 FMA-instructions -> VALU-bound.
__global__ __launch_bounds__(256, 2) void argmin_kernel(
    const float* __restrict__ x,       // [B][D][T]
    const float* __restrict__ embed,   // [K][D] row-major
    float* __restrict__ out_q,         // [B][D][T]
    float* __restrict__ out_idx,       // [B][T] (as float)
    float* __restrict__ counts,        // = out_avg region, pre-zeroed
    float* __restrict__ distsum)       // = out_commit slot, pre-zeroed
{
    __shared__ float xs[DIM][LDW];     // x tile [j][t], 33.8 KB
    __shared__ float es[DIM][LDW];     // e chunk [j][c], 33.8 KB; reused: red, gather
    __shared__ float e2all[KE];        // ||e_c||^2, 4 KB
    __shared__ int   ibest[128];

    const int tid = threadIdx.x;
    const int bid = blockIdx.x;
    const int b   = bid >> 4;          // 16 t-tiles of 128 per batch row
    const int t0  = (bid & 15) << 7;
    const int ti  = tid & 15;
    const int tj  = tid >> 4;

    // ---- stage x tile: xs[j][t] = x[b][j][t0+t] (coalesced float4) ----
    #pragma unroll
    for (int i = 0; i < 8; ++i) {
        const int f  = i * 256 + tid;  // float4 id: 64 rows x 32
        const int j  = f >> 5;
        const int c4 = (f & 31) * 4;
        const float4 v = *(const float4*)(x + (size_t)(b * DIM + j) * TT + t0 + c4);
        *(float4*)&xs[j][c4] = v;
    }

    // ---- e2 for all codes (embed is L2-hot across blocks) ----
    #pragma unroll
    for (int q = 0; q < 4; ++q) {
        const int c = q * 256 + tid;
        const float4* rp = (const float4*)(embed + (size_t)c * DIM);
        float s = 0.f;
        #pragma unroll
        for (int i = 0; i < 16; ++i) {
            const float4 v = rp[i];
            s += v.x * v.x + v.y * v.y + v.z * v.z + v.w * v.w;
        }
        e2all[c] = s;
    }

    float bestS[8], bestI[8];
    int   bi[8];
    #pragma unroll
    for (int a = 0; a < 8; ++a) { bestS[a] = FLT_MAX; bi[a] = 0; }
    (void)bestI;

    for (int kc = 0; kc < 8; ++kc) {
        __syncthreads();               // staging target free / prior reads done
        // stage es[j][r] = embed[kc*128+r][j] (coalesced float4 reads)
        {
            const int g  = tid & 15;
            const int r0 = tid >> 4;
            #pragma unroll
            for (int i = 0; i < 8; ++i) {
                const int r = r0 + 16 * i;
                const float4 v = *(const float4*)(embed + (size_t)(kc * 128 + r) * DIM + g * 4);
                es[g * 4 + 0][r] = v.x;
                es[g * 4 + 1][r] = v.y;
                es[g * 4 + 2][r] = v.z;
                es[g * 4 + 3][r] = v.w;
            }
        }
        __syncthreads();               // es ready

        float acc[8][8];
        #pragma unroll
        for (int a = 0; a < 8; ++a)
            #pragma unroll
            for (int q = 0; q < 8; ++q) acc[a][q] = 0.f;

        #pragma unroll 8
        for (int j = 0; j < DIM; ++j) {
            // x: two 4-quads at t = 4ti and 64+4ti  (2-way banks = free)
            const float4 xv0 = *(const float4*)&xs[j][ti * 4];
            const float4 xv1 = *(const float4*)&xs[j][64 + ti * 4];
            // e: 8 consecutive codes at c = 8tj (4 addrs/wave, 16-lane broadcast)
            const float4 ev0 = *(const float4*)&es[j][tj * 8];
            const float4 ev1 = *(const float4*)&es[j][tj * 8 + 4];
            const float xa[8] = {xv0.x, xv0.y, xv0.z, xv0.w, xv1.x, xv1.y, xv1.z, xv1.w};
            const float eb[8] = {ev0.x, ev0.y, ev0.z, ev0.w, ev1.x, ev1.y, ev1.z, ev1.w};
            #pragma unroll
            for (int a = 0; a < 8; ++a)
                #pragma unroll
                for (int q = 0; q < 8; ++q)
                    acc[a][q] = fmaf(xa[a], eb[q], acc[a][q]);
        }

        // epilogue: distances + running argmin (ascending c, strict <)
        const int cbase = kc * 128 + tj * 8;
        #pragma unroll
        for (int q = 0; q < 8; ++q) {
            const float e2 = e2all[cbase + q];
            #pragma unroll
            for (int a = 0; a < 8; ++a) {
                const float s = fmaf(-2.f, acc[a][q], e2);
                if (s < bestS[a]) { bestS[a] = s; bi[a] = cbase + q; }
            }
        }
    }

    // ---- cross-thread reduction over tj (reuse es as red_s/red_i) ----
    __syncthreads();                   // hot-loop es reads done
    float* red_s = &es[0][0];          // [128][17]
    int*   red_i = (int*)(&es[0][0] + 2176);
    #pragma unroll
    for (int a = 0; a < 8; ++a) {
        const int t = (a < 4) ? (ti * 4 + a) : (64 + ti * 4 + a - 4);
        red_s[t * 17 + tj] = bestS[a];
        red_i[t * 17 + tj] = bi[a];
    }
    __syncthreads();

    if (tid < 128) {
        const int t = tid;
        float bs = red_s[t * 17]; int bc = red_i[t * 17];
        #pragma unroll
        for (int q = 1; q < 16; ++q) {
            const float s = red_s[t * 17 + q]; const int i = red_i[t * 17 + q];
            if (s < bs || (s == bs && i < bc)) { bs = s; bc = i; }
        }
        float x2 = 0.f;
        #pragma unroll
        for (int j = 0; j < DIM; ++j) { const float v = xs[j][t]; x2 += v * v; }
        ibest[t] = bc;
        out_idx[b * TT + t0 + t] = (float)bc;
        atomicAdd(&counts[bc], 1.0f);
        float md = x2 + bs;            // ||x - e_best||^2
        #pragma unroll
        for (int off = 32; off > 0; off >>= 1) md += __shfl_down(md, off);
        if ((tid & 63) == 0) atomicAdd(distsum, md);
    }
    __syncthreads();                   // ibest ready; red reads done

    // ---- gather best rows into es[j][t], then coalesced transposed write ----
    {
        const int g  = tid & 15;
        const int r0 = tid >> 4;
        #pragma unroll
        for (int i = 0; i < 8; ++i) {
            const int t = r0 + 16 * i;
            const float4 v = *(const float4*)(embed + (size_t)ibest[t] * DIM + g * 4);
            es[g * 4 + 0][t] = v.x;
            es[g * 4 + 1][t] = v.y;
            es[g * 4 + 2][t] = v.z;
            es[g * 4 + 3][t] = v.w;
        }
    }
    __syncthreads();

    #pragma unroll
    for (int i = 0; i < 8; ++i) {
        const int f  = i * 256 + tid;
        const int j  = f >> 5;
        const int c4 = (f & 31) * 4;
        float4 w = *(const float4*)&es[j][c4];
        *(float4*)(out_q + (size_t)(b * DIM + j) * TT + t0 + c4) = w;
    }
}

// finalize: in-place counts->avg_probs, perplexity, usage, commitment
__global__ __launch_bounds__(1024) void finalize_kernel(
    float* __restrict__ avg,           // in: counts, out: probs
    float* __restrict__ commit_slot,   // in: distsum, out: commitment loss
    float* __restrict__ out_perp,
    float* __restrict__ out_usage)
{
    __shared__ float s_ent[1024];
    __shared__ float s_use[1024];
    const int k = threadIdx.x;
    const float p = avg[k] * (1.0f / (float)NTOT);
    avg[k] = p;
    s_ent[k] = p * logf(p + 1e-10f);
    s_use[k] = p * logf(p * 1024.f + 1e-10f);
    __syncthreads();
    for (int off = 512; off > 0; off >>= 1) {
        if (k < off) { s_ent[k] += s_ent[k + off]; s_use[k] += s_use[k + off]; }
        __syncthreads();
    }
    if (k == 0) {
        const float ds = commit_slot[0];
        *out_perp      = expf(-s_ent[0]);
        *out_usage     = s_use[0];
        commit_slot[0] = 0.25f * ds * (1.0f / ((float)NTOT * (float)DIM));
    }
}

extern "C" void kernel_launch(void* const* d_in, const int* in_sizes, int n_in,
                              void* d_out, int out_size, void* d_ws, size_t ws_size,
                              hipStream_t stream) {
    const float* x     = (const float*)d_in[0];
    const float* embed = (const float*)d_in[1];

    float* out        = (float*)d_out;
    float* out_q      = out;             // 4194304
    float* out_commit = out + 4194304;   // 1   (distsum accumulator first)
    float* out_perp   = out + 4194305;   // 1
    float* out_avg    = out + 4194306;   // 1024 (counts accumulator first)
    float* out_idx    = out + 4195330;   // 65536
    // usage at out + 4260866

    hipMemsetAsync(out_commit, 0, 1026 * sizeof(float), stream);
    argmin_kernel<<<512, 256, 0, stream>>>(x, embed, out_q, out_idx, out_avg, out_commit);
    finalize_kernel<<<1, 1024, 0, stream>>>(out_avg, out_commit, out_perp, out + 4260866);
}

// Round 5
// 153.006 us; speedup vs baseline: 1.6111x; 1.5965x over previous
//
#include <hip/hip_runtime.h>
#include <cfloat>
#include <cmath>

#define DIM 64
#define TT 2048
#define NTOT 65536
#define KE 1024

typedef _Float16 f16x8 __attribute__((ext_vector_type(8)));
typedef _Float16 f16x4 __attribute__((ext_vector_type(4)));
typedef float    f32x4 __attribute__((ext_vector_type(4)));

// LDS layout (bytes):
//  ep      : 4 planes-bufs [buf*2+plane][64 codes][72 halfs]  = 36864
//  e2s     : 1024 f32                                         = 4096
//  x2s     : 128 f32                                          = 512
//  ibest   : 128 i32                                          = 512
//  mdsum   : 1 f32 (+pad)
#define EP_ROW   72            // halfs per code row (144 B = 36 words, %32=4 rotation)
#define EP_PLANE 4608          // halfs per plane (64*72)
#define SMEM_BYTES (36864 + 4096 + 512 + 512 + 16)

// Block = 128 t x full K(1024 codes). 4 waves; wave w owns t in [w*32, w*32+32)
// as 2 M-tiles of 16. K in 16 chunks of 64 codes, fp16 hi/lo planes staged in
// LDS double-buffered. dot via 8 mfma_f32_16x16x32_f16 per MxN tile (exact
// fp16-split: x1e1+x1e2+x2e1+x2e2, small terms first).
__global__ __launch_bounds__(256, 2) void argmin_kernel(
    const float* __restrict__ x,       // [B][D][T]
    const float* __restrict__ embed,   // [K][D] row-major
    float* __restrict__ out_q,         // [B][D][T]
    float* __restrict__ out_idx,       // [B][T] (as float)
    float* __restrict__ counts,        // = out_avg region, pre-zeroed
    float* __restrict__ distsum)       // = out_commit slot, pre-zeroed
{
    __shared__ __align__(16) char smem[SMEM_BYTES];
    _Float16* ep  = (_Float16*)smem;
    float* e2s    = (float*)(smem + 36864);
    float* x2s    = (float*)(smem + 36864 + 4096);
    int*   ibest  = (int*)  (smem + 36864 + 4608);
    float* mdsum  = (float*)(smem + 36864 + 5120);

    const int tid = threadIdx.x;
    const int l   = tid & 63;
    const int w   = tid >> 6;
    const int q   = l >> 4;            // quad id (k-slice for A/B, row-group for C)
    const int ln  = l & 15;            // A: t-row ; B: code col ; C: code col
    const int bid = blockIdx.x;
    const int b   = bid >> 4;
    const int t0  = (bid & 15) << 7;

    if (tid == 0) mdsum[0] = 0.f;

    // ---- e2 for all 1024 codes (embed is L2-hot across blocks) ----
    #pragma unroll
    for (int pass = 0; pass < 4; ++pass) {
        const int c = pass * 256 + tid;
        const float4* rp = (const float4*)(embed + (size_t)c * DIM);
        float s = 0.f;
        #pragma unroll
        for (int i = 0; i < 16; ++i) {
            const float4 v = rp[i];
            s += v.x * v.x + v.y * v.y + v.z * v.z + v.w * v.w;
        }
        e2s[c] = s;
    }

    // ---- A fragments: x[t][j] for t = t0+w*32+m*16+ln, j = k*32+q*8+jj ----
    // fp16 split in registers; no LDS for A. af[plane][m][kstep]
    f16x8 af[2][2][2];
    float x2p[2] = {0.f, 0.f};
    #pragma unroll
    for (int m = 0; m < 2; ++m) {
        #pragma unroll
        for (int k = 0; k < 2; ++k) {
            #pragma unroll
            for (int jj = 0; jj < 8; ++jj) {
                const int j = k * 32 + q * 8 + jj;
                const float xf = x[(size_t)(b * DIM + j) * TT + t0 + w * 32 + m * 16 + ln];
                const _Float16 h1 = (_Float16)xf;          // RNE
                const float    r  = xf - (float)h1;        // exact (Sterbenz)
                af[0][m][k][jj] = h1;
                af[1][m][k][jj] = (_Float16)r;
                x2p[m] = fmaf(xf, xf, x2p[m]);
            }
        }
    }
    // full ||x_t||^2: combine the 4 k-slices (lanes differing in quad)
    #pragma unroll
    for (int m = 0; m < 2; ++m) {
        x2p[m] += __shfl_xor(x2p[m], 16);
        x2p[m] += __shfl_xor(x2p[m], 32);
    }
    if (q == 0) {
        x2s[w * 32 + ln]      = x2p[0];
        x2s[w * 32 + 16 + ln] = x2p[1];
    }

    // ---- stage chunk 0 into buf 0 ----
    {
        #pragma unroll
        for (int pass = 0; pass < 4; ++pass) {
            const int c_loc = (tid >> 4) + pass * 16;
            const int j4    = (tid & 15) * 4;
            const float4 v = *(const float4*)(embed + (size_t)c_loc * DIM + j4);
            f16x4 h1, h2;
            h1[0] = (_Float16)v.x; h2[0] = (_Float16)(v.x - (float)h1[0]);
            h1[1] = (_Float16)v.y; h2[1] = (_Float16)(v.y - (float)h1[1]);
            h1[2] = (_Float16)v.z; h2[2] = (_Float16)(v.z - (float)h1[2]);
            h1[3] = (_Float16)v.w; h2[3] = (_Float16)(v.w - (float)h1[3]);
            *(f16x4*)(ep + c_loc * EP_ROW + j4)            = h1;
            *(f16x4*)(ep + EP_PLANE + c_loc * EP_ROW + j4) = h2;
        }
    }
    __syncthreads();

    float bs[2][4];
    int   bi[2][4];
    #pragma unroll
    for (int m = 0; m < 2; ++m)
        #pragma unroll
        for (int r = 0; r < 4; ++r) { bs[m][r] = FLT_MAX; bi[m][r] = 0; }

    for (int kc = 0; kc < 16; ++kc) {
        const int cur = kc & 1;
        const int nxt = cur ^ 1;

        // prefetch next chunk (global, fp32)
        float4 ev[4];
        if (kc < 15) {
            #pragma unroll
            for (int pass = 0; pass < 4; ++pass) {
                const int c_loc = (tid >> 4) + pass * 16;
                const int j4    = (tid & 15) * 4;
                ev[pass] = *(const float4*)(embed + (size_t)((kc + 1) * 64 + c_loc) * DIM + j4);
            }
        }

        // compute: 4 N-steps of 16 codes on cur buffer
        const _Float16* p1 = ep + cur * 2 * EP_PLANE;
        const _Float16* p2 = p1 + EP_PLANE;
        #pragma unroll
        for (int n = 0; n < 4; ++n) {
            const int coff = (n * 16 + ln) * EP_ROW + q * 8;
            const f16x8 b1k0 = *(const f16x8*)(p1 + coff);
            const f16x8 b1k1 = *(const f16x8*)(p1 + coff + 32);
            const f16x8 b2k0 = *(const f16x8*)(p2 + coff);
            const f16x8 b2k1 = *(const f16x8*)(p2 + coff + 32);
            const int   c_lane = kc * 64 + n * 16 + ln;
            const float e2c    = e2s[c_lane];
            #pragma unroll
            for (int m = 0; m < 2; ++m) {
                f32x4 C = {0.f, 0.f, 0.f, 0.f};
                // small terms first, then large (accuracy)
                C = __builtin_amdgcn_mfma_f32_16x16x32_f16(af[1][m][0], b2k0, C, 0, 0, 0);
                C = __builtin_amdgcn_mfma_f32_16x16x32_f16(af[1][m][1], b2k1, C, 0, 0, 0);
                C = __builtin_amdgcn_mfma_f32_16x16x32_f16(af[1][m][0], b1k0, C, 0, 0, 0);
                C = __builtin_amdgcn_mfma_f32_16x16x32_f16(af[1][m][1], b1k1, C, 0, 0, 0);
                C = __builtin_amdgcn_mfma_f32_16x16x32_f16(af[0][m][0], b2k0, C, 0, 0, 0);
                C = __builtin_amdgcn_mfma_f32_16x16x32_f16(af[0][m][1], b2k1, C, 0, 0, 0);
                C = __builtin_amdgcn_mfma_f32_16x16x32_f16(af[0][m][0], b1k0, C, 0, 0, 0);
                C = __builtin_amdgcn_mfma_f32_16x16x32_f16(af[0][m][1], b1k1, C, 0, 0, 0);
                #pragma unroll
                for (int r = 0; r < 4; ++r) {
                    const float s = fmaf(-2.f, C[r], e2c);
                    // ascending c_lane + strict < keeps lowest index on ties
                    if (s < bs[m][r]) { bs[m][r] = s; bi[m][r] = c_lane; }
                }
            }
        }

        // convert + write next chunk into nxt buffer
        if (kc < 15) {
            _Float16* w1 = ep + nxt * 2 * EP_PLANE;
            _Float16* w2 = w1 + EP_PLANE;
            #pragma unroll
            for (int pass = 0; pass < 4; ++pass) {
                const int c_loc = (tid >> 4) + pass * 16;
                const int j4    = (tid & 15) * 4;
                const float4 v = ev[pass];
                f16x4 h1, h2;
                h1[0] = (_Float16)v.x; h2[0] = (_Float16)(v.x - (float)h1[0]);
                h1[1] = (_Float16)v.y; h2[1] = (_Float16)(v.y - (float)h1[1]);
                h1[2] = (_Float16)v.z; h2[2] = (_Float16)(v.z - (float)h1[2]);
                h1[3] = (_Float16)v.w; h2[3] = (_Float16)(v.w - (float)h1[3]);
                *(f16x4*)(w1 + c_loc * EP_ROW + j4) = h1;
                *(f16x4*)(w2 + c_loc * EP_ROW + j4) = h2;
            }
        }
        __syncthreads();
    }

    // ---- argmin reduce across the 16 code-columns of each quad ----
    float mdloc = 0.f;
    #pragma unroll
    for (int m = 0; m < 2; ++m) {
        #pragma unroll
        for (int r = 0; r < 4; ++r) {
            float s = bs[m][r]; int i = bi[m][r];
            #pragma unroll
            for (int mask = 1; mask < 16; mask <<= 1) {
                const float s2 = __shfl_xor(s, mask);
                const int   i2 = __shfl_xor(i, mask);
                if (s2 < s || (s2 == s && i2 < i)) { s = s2; i = i2; }
            }
            if (ln == 0) {
                const int t_loc = w * 32 + m * 16 + q * 4 + r;   // C-row map
                ibest[t_loc] = i;
                out_idx[b * TT + t0 + t_loc] = (float)i;
                atomicAdd(&counts[i], 1.0f);
                mdloc += x2s[t_loc] + s;                          // ||x-e||^2
            }
        }
    }
    if (ln == 0) atomicAdd(mdsum, mdloc);
    __syncthreads();
    if (tid == 0) atomicAdd(distsum, mdsum[0]);

    // ---- quantized gather: out_q[b][j][t0+tt] = embed[ibest[tt]][j] ----
    #pragma unroll
    for (int p = 0; p < 32; ++p) {
        const int f  = p * 256 + tid;
        const int j  = f >> 7;
        const int tt = f & 127;
        out_q[(size_t)(b * DIM + j) * TT + t0 + tt] =
            embed[(size_t)ibest[tt] * DIM + j];
    }
}

// finalize: in-place counts->avg_probs, perplexity, usage, commitment
__global__ __launch_bounds__(1024) void finalize_kernel(
    float* __restrict__ avg,           // in: counts, out: probs
    float* __restrict__ commit_slot,   // in: distsum, out: commitment loss
    float* __restrict__ out_perp,
    float* __restrict__ out_usage)
{
    __shared__ float s_ent[1024];
    __shared__ float s_use[1024];
    const int k = threadIdx.x;
    const float p = avg[k] * (1.0f / (float)NTOT);
    avg[k] = p;
    s_ent[k] = p * logf(p + 1e-10f);
    s_use[k] = p * logf(p * 1024.f + 1e-10f);
    __syncthreads();
    for (int off = 512; off > 0; off >>= 1) {
        if (k < off) { s_ent[k] += s_ent[k + off]; s_use[k] += s_use[k + off]; }
        __syncthreads();
    }
    if (k == 0) {
        const float ds = commit_slot[0];
        *out_perp      = expf(-s_ent[0]);
        *out_usage     = s_use[0];
        commit_slot[0] = 0.25f * ds * (1.0f / ((float)NTOT * (float)DIM));
    }
}

extern "C" void kernel_launch(void* const* d_in, const int* in_sizes, int n_in,
                              void* d_out, int out_size, void* d_ws, size_t ws_size,
                              hipStream_t stream) {
    const float* x     = (const float*)d_in[0];
    const float* embed = (const float*)d_in[1];

    float* out        = (float*)d_out;
    float* out_q      = out;             // 4194304
    float* out_commit = out + 4194304;   // 1   (distsum accumulator first)
    float* out_perp   = out + 4194305;   // 1
    float* out_avg    = out + 4194306;   // 1024 (counts accumulator first)
    float* out_idx    = out + 4195330;   // 65536
    // usage at out + 4260866

    hipMemsetAsync(out_commit, 0, 1026 * sizeof(float), stream);
    argmin_kernel<<<512, 256, 0, stream>>>(x, embed, out_q, out_idx, out_avg, out_commit);
    finalize_kernel<<<1, 1024, 0, stream>>>(out_avg, out_commit, out_perp, out + 4260866);
}

// Round 6
// 150.500 us; speedup vs baseline: 1.6380x; 1.0167x over previous
//
#include <hip/hip_runtime.h>
#include <cfloat>
#include <cmath>

#define DIM 64
#define TT 2048
#define NTOT 65536
#define KE 1024

typedef _Float16 f16x8 __attribute__((ext_vector_type(8)));
typedef _Float16 f16x4 __attribute__((ext_vector_type(4)));
typedef float    f32x4 __attribute__((ext_vector_type(4)));

// ws layout (bytes): fp16 plane0 [0,131072), plane1 [131072,262144), e2 [262144,266240)
// plane vector layout: f16x8 index ((g*2+k)*64 + l)  for group g(16 codes), kstep k, lane l.
// lane l = q*16+ln holds embed_plane[c = g*16+ln][j = k*32 + q*8 + 0..7]  (B-fragment-ready,
// mapping verified by Round-5 pass).
#define WS_NEED 266240

// ============================ fast path ====================================
__global__ __launch_bounds__(256) void prep_kernel(
    const float* __restrict__ embed,
    _Float16* __restrict__ planes,     // d_ws
    float* __restrict__ e2g,           // d_ws + 262144B
    float* __restrict__ counts,        // out_avg region  (zeroed here)
    float* __restrict__ distsum)       // out_commit slot (zeroed here)
{
    const int gidx = blockIdx.x * 256 + threadIdx.x;   // 8192 threads
    const int g  = gidx >> 7;
    const int k  = (gidx >> 6) & 1;
    const int l  = gidx & 63;
    const int q  = l >> 4;
    const int ln = l & 15;
    const int c  = g * 16 + ln;
    const int jb = k * 32 + q * 8;

    const float4 v0 = *(const float4*)(embed + (size_t)c * DIM + jb);
    const float4 v1 = *(const float4*)(embed + (size_t)c * DIM + jb + 4);
    const float xf[8] = {v0.x, v0.y, v0.z, v0.w, v1.x, v1.y, v1.z, v1.w};
    f16x8 h1, h2;
    #pragma unroll
    for (int e = 0; e < 8; ++e) {
        const _Float16 a = (_Float16)xf[e];
        h1[e] = a;
        h2[e] = (_Float16)(xf[e] - (float)a);   // exact residual (Sterbenz)
    }
    const int off = ((g * 2 + k) * 64 + l) * 8;
    *(f16x8*)(planes + off)         = h1;
    *(f16x8*)(planes + 65536 + off) = h2;

    if (gidx < KE) {
        const float4* rp = (const float4*)(embed + (size_t)gidx * DIM);
        float s = 0.f;
        #pragma unroll
        for (int i = 0; i < 16; ++i) {
            const float4 v = rp[i];
            s += v.x * v.x + v.y * v.y + v.z * v.z + v.w * v.w;
        }
        e2g[gidx]    = s;
        counts[gidx] = 0.f;
        if (gidx == 0) distsum[0] = 0.f;
    }
}

// Block = 128 t x full K. 4 waves; wave w owns t in [w*32,w*32+32) as 2 M-tiles.
// B fragments read directly from ws planes (L2-hot, coalesced 1KB/wave-load).
// NO LDS staging, NO barriers in the hot loop.
__global__ __launch_bounds__(256, 2) void argmin_fast(
    const float* __restrict__ x,       // [B][D][T]
    const float* __restrict__ embed,   // [K][D] fp32 (for gather)
    const f16x8* __restrict__ P,       // ws planes as f16x8 vectors
    const float* __restrict__ e2g,     // ws e2
    float* __restrict__ out_q,
    float* __restrict__ out_idx,
    float* __restrict__ counts,        // pre-zeroed by prep
    float* __restrict__ distsum)       // pre-zeroed by prep
{
    __shared__ float e2s[KE];
    __shared__ float x2s[128];
    __shared__ int   ibest[128];
    __shared__ float mdsum[1];

    const int tid = threadIdx.x;
    const int l   = tid & 63;
    const int w   = tid >> 6;
    const int q   = l >> 4;
    const int ln  = l & 15;
    const int bid = blockIdx.x;
    const int b   = bid >> 4;
    const int t0  = (bid & 15) << 7;

    if (tid == 0) mdsum[0] = 0.f;
    {   // e2 -> LDS (one barrier, only one in the whole kernel before epilogue)
        const float4 v = *(const float4*)(e2g + tid * 4);
        *(float4*)(e2s + tid * 4) = v;
    }

    // ---- A fragments: fp16 split in registers (layout verified Round 5) ----
    f16x8 af[2][2][2];                 // [plane][m][k]
    float x2p[2] = {0.f, 0.f};
    #pragma unroll
    for (int m = 0; m < 2; ++m) {
        #pragma unroll
        for (int k = 0; k < 2; ++k) {
            #pragma unroll
            for (int jj = 0; jj < 8; ++jj) {
                const int j = k * 32 + q * 8 + jj;
                const float xf = x[(size_t)(b * DIM + j) * TT + t0 + w * 32 + m * 16 + ln];
                const _Float16 h1 = (_Float16)xf;
                af[0][m][k][jj] = h1;
                af[1][m][k][jj] = (_Float16)(xf - (float)h1);
                x2p[m] = fmaf(xf, xf, x2p[m]);
            }
        }
    }
    #pragma unroll
    for (int m = 0; m < 2; ++m) {
        x2p[m] += __shfl_xor(x2p[m], 16);
        x2p[m] += __shfl_xor(x2p[m], 32);
    }
    if (q == 0) {
        x2s[w * 32 + ln]      = x2p[0];
        x2s[w * 32 + 16 + ln] = x2p[1];
    }
    __syncthreads();                   // e2s + x2s ready

    float bs[2][4];
    int   bi[2][4];
    #pragma unroll
    for (int m = 0; m < 2; ++m)
        #pragma unroll
        for (int r = 0; r < 4; ++r) { bs[m][r] = FLT_MAX; bi[m][r] = 0; }

    // ---- hot loop: 64 groups of 16 codes, software-pipelined prefetch ----
    const f16x8* base = P + l;
    f16x8 c1k0 = base[0], c1k1 = base[64], c2k0 = base[8192], c2k1 = base[8192 + 64];
    #pragma unroll 2
    for (int g = 0; g < 64; ++g) {
        f16x8 n1k0, n1k1, n2k0, n2k1;
        if (g < 63) {
            const f16x8* nb = base + (g + 1) * 128;
            n1k0 = nb[0]; n1k1 = nb[64]; n2k0 = nb[8192]; n2k1 = nb[8192 + 64];
        }
        const float e2c = e2s[g * 16 + ln];
        const int c_lane = g * 16 + ln;
        #pragma unroll
        for (int m = 0; m < 2; ++m) {
            f32x4 C = {0.f, 0.f, 0.f, 0.f};
            // small terms first for accuracy
            C = __builtin_amdgcn_mfma_f32_16x16x32_f16(af[1][m][0], c2k0, C, 0, 0, 0);
            C = __builtin_amdgcn_mfma_f32_16x16x32_f16(af[1][m][1], c2k1, C, 0, 0, 0);
            C = __builtin_amdgcn_mfma_f32_16x16x32_f16(af[1][m][0], c1k0, C, 0, 0, 0);
            C = __builtin_amdgcn_mfma_f32_16x16x32_f16(af[1][m][1], c1k1, C, 0, 0, 0);
            C = __builtin_amdgcn_mfma_f32_16x16x32_f16(af[0][m][0], c2k0, C, 0, 0, 0);
            C = __builtin_amdgcn_mfma_f32_16x16x32_f16(af[0][m][1], c2k1, C, 0, 0, 0);
            C = __builtin_amdgcn_mfma_f32_16x16x32_f16(af[0][m][0], c1k0, C, 0, 0, 0);
            C = __builtin_amdgcn_mfma_f32_16x16x32_f16(af[0][m][1], c1k1, C, 0, 0, 0);
            #pragma unroll
            for (int r = 0; r < 4; ++r) {
                const float s = fmaf(-2.f, C[r], e2c);
                // strict < + ascending c keeps lowest index on ties (numpy argmin)
                if (s < bs[m][r]) { bs[m][r] = s; bi[m][r] = c_lane; }
            }
        }
        c1k0 = n1k0; c1k1 = n1k1; c2k0 = n2k0; c2k1 = n2k1;
    }

    // ---- argmin reduce across the 16 code-columns of each quad ----
    float mdloc = 0.f;
    #pragma unroll
    for (int m = 0; m < 2; ++m) {
        #pragma unroll
        for (int r = 0; r < 4; ++r) {
            float s = bs[m][r]; int i = bi[m][r];
            #pragma unroll
            for (int mask = 1; mask < 16; mask <<= 1) {
                const float s2 = __shfl_xor(s, mask);
                const int   i2 = __shfl_xor(i, mask);
                if (s2 < s || (s2 == s && i2 < i)) { s = s2; i = i2; }
            }
            if (ln == 0) {
                const int t_loc = w * 32 + m * 16 + q * 4 + r;   // C-row map (verified)
                ibest[t_loc] = i;
                out_idx[b * TT + t0 + t_loc] = (float)i;
                atomicAdd(&counts[i], 1.0f);
                mdloc += x2s[t_loc] + s;
            }
        }
    }
    if (ln == 0) atomicAdd(mdsum, mdloc);
    __syncthreads();
    if (tid == 0) atomicAdd(distsum, mdsum[0]);

    // ---- quantized gather: out_q[b][j][t0+tt] = embed[ibest[tt]][j] ----
    #pragma unroll
    for (int p = 0; p < 32; ++p) {
        const int f  = p * 256 + tid;
        const int j  = f >> 7;
        const int tt = f & 127;
        out_q[(size_t)(b * DIM + j) * TT + t0 + tt] =
            embed[(size_t)ibest[tt] * DIM + j];
    }
}

// ======================= fallback path (Round-5, passed) ====================
#define EP_ROW   72
#define EP_PLANE 4608
#define SMEM_BYTES (36864 + 4096 + 512 + 512 + 16)

__global__ __launch_bounds__(256, 2) void argmin_fb(
    const float* __restrict__ x, const float* __restrict__ embed,
    float* __restrict__ out_q, float* __restrict__ out_idx,
    float* __restrict__ counts, float* __restrict__ distsum)
{
    __shared__ __align__(16) char smem[SMEM_BYTES];
    _Float16* ep  = (_Float16*)smem;
    float* e2s    = (float*)(smem + 36864);
    float* x2s    = (float*)(smem + 36864 + 4096);
    int*   ibest  = (int*)  (smem + 36864 + 4608);
    float* mdsum  = (float*)(smem + 36864 + 5120);

    const int tid = threadIdx.x;
    const int l   = tid & 63;
    const int w   = tid >> 6;
    const int q   = l >> 4;
    const int ln  = l & 15;
    const int bid = blockIdx.x;
    const int b   = bid >> 4;
    const int t0  = (bid & 15) << 7;

    if (tid == 0) mdsum[0] = 0.f;
    #pragma unroll
    for (int pass = 0; pass < 4; ++pass) {
        const int c = pass * 256 + tid;
        const float4* rp = (const float4*)(embed + (size_t)c * DIM);
        float s = 0.f;
        #pragma unroll
        for (int i = 0; i < 16; ++i) {
            const float4 v = rp[i];
            s += v.x * v.x + v.y * v.y + v.z * v.z + v.w * v.w;
        }
        e2s[c] = s;
    }
    f16x8 af[2][2][2];
    float x2p[2] = {0.f, 0.f};
    #pragma unroll
    for (int m = 0; m < 2; ++m)
        #pragma unroll
        for (int k = 0; k < 2; ++k)
            #pragma unroll
            for (int jj = 0; jj < 8; ++jj) {
                const int j = k * 32 + q * 8 + jj;
                const float xf = x[(size_t)(b * DIM + j) * TT + t0 + w * 32 + m * 16 + ln];
                const _Float16 h1 = (_Float16)xf;
                af[0][m][k][jj] = h1;
                af[1][m][k][jj] = (_Float16)(xf - (float)h1);
                x2p[m] = fmaf(xf, xf, x2p[m]);
            }
    #pragma unroll
    for (int m = 0; m < 2; ++m) {
        x2p[m] += __shfl_xor(x2p[m], 16);
        x2p[m] += __shfl_xor(x2p[m], 32);
    }
    if (q == 0) { x2s[w * 32 + ln] = x2p[0]; x2s[w * 32 + 16 + ln] = x2p[1]; }
    {
        #pragma unroll
        for (int pass = 0; pass < 4; ++pass) {
            const int c_loc = (tid >> 4) + pass * 16;
            const int j4    = (tid & 15) * 4;
            const float4 v = *(const float4*)(embed + (size_t)c_loc * DIM + j4);
            f16x4 h1, h2;
            h1[0] = (_Float16)v.x; h2[0] = (_Float16)(v.x - (float)h1[0]);
            h1[1] = (_Float16)v.y; h2[1] = (_Float16)(v.y - (float)h1[1]);
            h1[2] = (_Float16)v.z; h2[2] = (_Float16)(v.z - (float)h1[2]);
            h1[3] = (_Float16)v.w; h2[3] = (_Float16)(v.w - (float)h1[3]);
            *(f16x4*)(ep + c_loc * EP_ROW + j4)            = h1;
            *(f16x4*)(ep + EP_PLANE + c_loc * EP_ROW + j4) = h2;
        }
    }
    __syncthreads();
    float bs[2][4]; int bi[2][4];
    #pragma unroll
    for (int m = 0; m < 2; ++m)
        #pragma unroll
        for (int r = 0; r < 4; ++r) { bs[m][r] = FLT_MAX; bi[m][r] = 0; }
    for (int kc = 0; kc < 16; ++kc) {
        const int cur = kc & 1, nxt = cur ^ 1;
        float4 ev[4];
        if (kc < 15)
            #pragma unroll
            for (int pass = 0; pass < 4; ++pass) {
                const int c_loc = (tid >> 4) + pass * 16;
                const int j4    = (tid & 15) * 4;
                ev[pass] = *(const float4*)(embed + (size_t)((kc + 1) * 64 + c_loc) * DIM + j4);
            }
        const _Float16* p1 = ep + cur * 2 * EP_PLANE;
        const _Float16* p2 = p1 + EP_PLANE;
        #pragma unroll
        for (int n = 0; n < 4; ++n) {
            const int coff = (n * 16 + ln) * EP_ROW + q * 8;
            const f16x8 b1k0 = *(const f16x8*)(p1 + coff);
            const f16x8 b1k1 = *(const f16x8*)(p1 + coff + 32);
            const f16x8 b2k0 = *(const f16x8*)(p2 + coff);
            const f16x8 b2k1 = *(const f16x8*)(p2 + coff + 32);
            const int   c_lane = kc * 64 + n * 16 + ln;
            const float e2c    = e2s[c_lane];
            #pragma unroll
            for (int m = 0; m < 2; ++m) {
                f32x4 C = {0.f, 0.f, 0.f, 0.f};
                C = __builtin_amdgcn_mfma_f32_16x16x32_f16(af[1][m][0], b2k0, C, 0, 0, 0);
                C = __builtin_amdgcn_mfma_f32_16x16x32_f16(af[1][m][1], b2k1, C, 0, 0, 0);
                C = __builtin_amdgcn_mfma_f32_16x16x32_f16(af[1][m][0], b1k0, C, 0, 0, 0);
                C = __builtin_amdgcn_mfma_f32_16x16x32_f16(af[1][m][1], b1k1, C, 0, 0, 0);
                C = __builtin_amdgcn_mfma_f32_16x16x32_f16(af[0][m][0], b2k0, C, 0, 0, 0);
                C = __builtin_amdgcn_mfma_f32_16x16x32_f16(af[0][m][1], b2k1, C, 0, 0, 0);
                C = __builtin_amdgcn_mfma_f32_16x16x32_f16(af[0][m][0], b1k0, C, 0, 0, 0);
                C = __builtin_amdgcn_mfma_f32_16x16x32_f16(af[0][m][1], b1k1, C, 0, 0, 0);
                #pragma unroll
                for (int r = 0; r < 4; ++r) {
                    const float s = fmaf(-2.f, C[r], e2c);
                    if (s < bs[m][r]) { bs[m][r] = s; bi[m][r] = c_lane; }
                }
            }
        }
        if (kc < 15) {
            _Float16* w1 = ep + nxt * 2 * EP_PLANE;
            _Float16* w2 = w1 + EP_PLANE;
            #pragma unroll
            for (int pass = 0; pass < 4; ++pass) {
                const int c_loc = (tid >> 4) + pass * 16;
                const int j4    = (tid & 15) * 4;
                const float4 v = ev[pass];
                f16x4 h1, h2;
                h1[0] = (_Float16)v.x; h2[0] = (_Float16)(v.x - (float)h1[0]);
                h1[1] = (_Float16)v.y; h2[1] = (_Float16)(v.y - (float)h1[1]);
                h1[2] = (_Float16)v.z; h2[2] = (_Float16)(v.z - (float)h1[2]);
                h1[3] = (_Float16)v.w; h2[3] = (_Float16)(v.w - (float)h1[3]);
                *(f16x4*)(w1 + c_loc * EP_ROW + j4) = h1;
                *(f16x4*)(w2 + c_loc * EP_ROW + j4) = h2;
            }
        }
        __syncthreads();
    }
    float mdloc = 0.f;
    #pragma unroll
    for (int m = 0; m < 2; ++m)
        #pragma unroll
        for (int r = 0; r < 4; ++r) {
            float s = bs[m][r]; int i = bi[m][r];
            #pragma unroll
            for (int mask = 1; mask < 16; mask <<= 1) {
                const float s2 = __shfl_xor(s, mask);
                const int   i2 = __shfl_xor(i, mask);
                if (s2 < s || (s2 == s && i2 < i)) { s = s2; i = i2; }
            }
            if (ln == 0) {
                const int t_loc = w * 32 + m * 16 + q * 4 + r;
                ibest[t_loc] = i;
                out_idx[b * TT + t0 + t_loc] = (float)i;
                atomicAdd(&counts[i], 1.0f);
                mdloc += x2s[t_loc] + s;
            }
        }
    if (ln == 0) atomicAdd(mdsum, mdloc);
    __syncthreads();
    if (tid == 0) atomicAdd(distsum, mdsum[0]);
    #pragma unroll
    for (int p = 0; p < 32; ++p) {
        const int f  = p * 256 + tid;
        const int j  = f >> 7;
        const int tt = f & 127;
        out_q[(size_t)(b * DIM + j) * TT + t0 + tt] =
            embed[(size_t)ibest[tt] * DIM + j];
    }
}

// finalize: in-place counts->avg_probs, perplexity, usage, commitment
__global__ __launch_bounds__(1024) void finalize_kernel(
    float* __restrict__ avg, float* __restrict__ commit_slot,
    float* __restrict__ out_perp, float* __restrict__ out_usage)
{
    __shared__ float s_ent[1024];
    __shared__ float s_use[1024];
    const int k = threadIdx.x;
    const float p = avg[k] * (1.0f / (float)NTOT);
    avg[k] = p;
    s_ent[k] = p * logf(p + 1e-10f);
    s_use[k] = p * logf(p * 1024.f + 1e-10f);
    __syncthreads();
    for (int off = 512; off > 0; off >>= 1) {
        if (k < off) { s_ent[k] += s_ent[k + off]; s_use[k] += s_use[k + off]; }
        __syncthreads();
    }
    if (k == 0) {
        const float ds = commit_slot[0];
        *out_perp      = expf(-s_ent[0]);
        *out_usage     = s_use[0];
        commit_slot[0] = 0.25f * ds * (1.0f / ((float)NTOT * (float)DIM));
    }
}

extern "C" void kernel_launch(void* const* d_in, const int* in_sizes, int n_in,
                              void* d_out, int out_size, void* d_ws, size_t ws_size,
                              hipStream_t stream) {
    const float* x     = (const float*)d_in[0];
    const float* embed = (const float*)d_in[1];

    float* out        = (float*)d_out;
    float* out_q      = out;             // 4194304
    float* out_commit = out + 4194304;   // distsum accumulator first
    float* out_perp   = out + 4194305;
    float* out_avg    = out + 4194306;   // counts accumulator first
    float* out_idx    = out + 4195330;
    // usage at out + 4260866

    if (ws_size >= WS_NEED) {
        _Float16* planes = (_Float16*)d_ws;
        float*    e2g    = (float*)((char*)d_ws + 262144);
        prep_kernel<<<32, 256, 0, stream>>>(embed, planes, e2g, out_avg, out_commit);
        argmin_fast<<<512, 256, 0, stream>>>(x, embed, (const f16x8*)planes, e2g,
                                             out_q, out_idx, out_avg, out_commit);
    } else {
        hipMemsetAsync(out_commit, 0, 1026 * sizeof(float), stream);
        argmin_fb<<<512, 256, 0, stream>>>(x, embed, out_q, out_idx, out_avg, out_commit);
    }
    finalize_kernel<<<1, 1024, 0, stream>>>(out_avg, out_commit, out_perp, out + 4260866);
}

// Round 7
// 145.168 us; speedup vs baseline: 1.6981x; 1.0367x over previous
//
#include <hip/hip_runtime.h>
#include <cfloat>
#include <cmath>

#define DIM 64
#define TT 2048
#define NTOT 65536
#define KE 1024

typedef _Float16 f16x8 __attribute__((ext_vector_type(8)));
typedef _Float16 f16x4 __attribute__((ext_vector_type(4)));
typedef float    f32x4 __attribute__((ext_vector_type(4)));

// ws layout (bytes):
//   keys   [0, 524288)        : 65536 u64, one per t, init 0xFF..F
//   planes [524288, 786432)   : fp16 hi plane (131072 B) + lo plane (131072 B)
//   e2     [786432, 790528)   : 1024 f32
// plane vector layout (B-fragment-ready, verified R5/R6): f16x8 index
//   ((g*2+k)*64 + l) for group g (16 codes), kstep k, lane l=q*16+ln holding
//   embed_plane[c=g*16+ln][j=k*32+q*8 .. +7].
#define WS_NEED 790528

// ============================ fast path ====================================
__global__ __launch_bounds__(256) void prep_kernel(
    const float* __restrict__ embed,
    _Float16* __restrict__ planes,
    float* __restrict__ e2g,
    unsigned long long* __restrict__ keys,
    float* __restrict__ counts,        // out_avg region  (zeroed here)
    float* __restrict__ distsum)       // out_commit slot (zeroed here)
{
    const int gidx = blockIdx.x * 256 + threadIdx.x;   // 8192 threads
    const int g  = gidx >> 7;
    const int k  = (gidx >> 6) & 1;
    const int l  = gidx & 63;
    const int q  = l >> 4;
    const int ln = l & 15;
    const int c  = g * 16 + ln;
    const int jb = k * 32 + q * 8;

    const float4 v0 = *(const float4*)(embed + (size_t)c * DIM + jb);
    const float4 v1 = *(const float4*)(embed + (size_t)c * DIM + jb + 4);
    const float xf[8] = {v0.x, v0.y, v0.z, v0.w, v1.x, v1.y, v1.z, v1.w};
    f16x8 h1, h2;
    #pragma unroll
    for (int e = 0; e < 8; ++e) {
        const _Float16 a = (_Float16)xf[e];
        h1[e] = a;
        h2[e] = (_Float16)(xf[e] - (float)a);   // exact residual
    }
    const int off = ((g * 2 + k) * 64 + l) * 8;
    *(f16x8*)(planes + off)         = h1;
    *(f16x8*)(planes + 65536 + off) = h2;

    // keys init (coalesced)
    #pragma unroll
    for (int i = 0; i < 8; ++i) keys[(size_t)i * 8192 + gidx] = ~0ull;

    if (gidx < KE) {
        const float4* rp = (const float4*)(embed + (size_t)gidx * DIM);
        float s = 0.f;
        #pragma unroll
        for (int i = 0; i < 16; ++i) {
            const float4 v = rp[i];
            s += v.x * v.x + v.y * v.y + v.z * v.z + v.w * v.w;
        }
        e2g[gidx]    = s;
        counts[gidx] = 0.f;
        if (gidx == 0) distsum[0] = 0.f;
    }
}

// Pass 1: grid 1024 = 512 t-tiles x 2 K-halves. Block = 128 t x 512 codes.
// 4 blocks/CU (16 waves/CU) -> TLP hides L2 latency. Per-t result merged
// across K-halves via u64 atomicMin on packed (monotone(s), idx) keys.
__global__ __launch_bounds__(256, 4) void argmin_p1(
    const float* __restrict__ x,       // [B][D][T]
    const f16x8* __restrict__ P,       // ws planes
    const float* __restrict__ e2g,     // ws e2
    unsigned long long* __restrict__ keys,
    float* __restrict__ distsum)       // += sum(x^2) from kq==0 blocks
{
    __shared__ float e2s[512];
    __shared__ float x2acc[1];

    const int tid  = threadIdx.x;
    const int l    = tid & 63;
    const int w    = tid >> 6;
    const int q    = l >> 4;
    const int ln   = l & 15;
    const int bid  = blockIdx.x;
    const int kq   = bid & 1;          // K-half
    const int tile = bid >> 1;
    const int b    = tile >> 4;
    const int t0   = (tile & 15) << 7;

    if (tid == 0) x2acc[0] = 0.f;
    if (tid < 128)
        *(float4*)&e2s[tid * 4] = *(const float4*)(e2g + kq * 512 + tid * 4);

    // ---- A fragments: fp16 split in registers (layout verified R5/R6) ----
    f16x8 af[2][2][2];                 // [plane][m][k]
    float x2p[2] = {0.f, 0.f};
    #pragma unroll
    for (int m = 0; m < 2; ++m)
        #pragma unroll
        for (int k = 0; k < 2; ++k)
            #pragma unroll
            for (int jj = 0; jj < 8; ++jj) {
                const int j = k * 32 + q * 8 + jj;
                const float xf = x[(size_t)(b * DIM + j) * TT + t0 + w * 32 + m * 16 + ln];
                const _Float16 h1 = (_Float16)xf;
                af[0][m][k][jj] = h1;
                af[1][m][k][jj] = (_Float16)(xf - (float)h1);
                x2p[m] = fmaf(xf, xf, x2p[m]);
            }
    __syncthreads();                   // e2s ready

    float bs[2][4];
    int   bi[2][4];
    #pragma unroll
    for (int m = 0; m < 2; ++m)
        #pragma unroll
        for (int r = 0; r < 4; ++r) { bs[m][r] = FLT_MAX; bi[m][r] = 0; }

    // ---- hot loop: 32 groups of 16 codes from this K-half ----
    const f16x8* base = P + l + kq * 4096;
    for (int gl = 0; gl < 32; ++gl) {
        const f16x8* gp = base + gl * 128;
        const f16x8 b1k0 = gp[0];
        const f16x8 b1k1 = gp[64];
        const f16x8 b2k0 = gp[8192];
        const f16x8 b2k1 = gp[8192 + 64];
        const int   cl   = gl * 16 + ln;
        const float e2c  = e2s[cl];
        const int   cgl  = kq * 512 + cl;
        #pragma unroll
        for (int m = 0; m < 2; ++m) {
            f32x4 C = {0.f, 0.f, 0.f, 0.f};
            // small terms first for accuracy (verified R5/R6 ordering)
            C = __builtin_amdgcn_mfma_f32_16x16x32_f16(af[1][m][0], b2k0, C, 0, 0, 0);
            C = __builtin_amdgcn_mfma_f32_16x16x32_f16(af[1][m][1], b2k1, C, 0, 0, 0);
            C = __builtin_amdgcn_mfma_f32_16x16x32_f16(af[1][m][0], b1k0, C, 0, 0, 0);
            C = __builtin_amdgcn_mfma_f32_16x16x32_f16(af[1][m][1], b1k1, C, 0, 0, 0);
            C = __builtin_amdgcn_mfma_f32_16x16x32_f16(af[0][m][0], b2k0, C, 0, 0, 0);
            C = __builtin_amdgcn_mfma_f32_16x16x32_f16(af[0][m][1], b2k1, C, 0, 0, 0);
            C = __builtin_amdgcn_mfma_f32_16x16x32_f16(af[0][m][0], b1k0, C, 0, 0, 0);
            C = __builtin_amdgcn_mfma_f32_16x16x32_f16(af[0][m][1], b1k1, C, 0, 0, 0);
            #pragma unroll
            for (int r = 0; r < 4; ++r) {
                const float s = fmaf(-2.f, C[r], e2c);
                // strict < + ascending c keeps lowest index on ties
                if (s < bs[m][r]) { bs[m][r] = s; bi[m][r] = cgl; }
            }
        }
    }

    // ---- reduce over the 16 code-columns, then device-wide atomicMin ----
    #pragma unroll
    for (int m = 0; m < 2; ++m)
        #pragma unroll
        for (int r = 0; r < 4; ++r) {
            float s = bs[m][r]; int i = bi[m][r];
            #pragma unroll
            for (int mask = 1; mask < 16; mask <<= 1) {
                const float s2 = __shfl_xor(s, mask);
                const int   i2 = __shfl_xor(i, mask);
                if (s2 < s || (s2 == s && i2 < i)) { s = s2; i = i2; }
            }
            if (ln == 0) {
                const int t_loc = w * 32 + m * 16 + q * 4 + r;   // C-row map (verified)
                unsigned int sb = __float_as_uint(s);
                sb = sb ^ (((unsigned int)(((int)sb) >> 31)) | 0x80000000u);
                const unsigned long long key =
                    ((unsigned long long)sb << 32) | (unsigned int)i;
                atomicMin(&keys[(size_t)b * TT + t0 + t_loc], key);
            }
        }

    // ---- sum(x^2) contribution (kq==0 blocks only; each t counted 4x) ----
    if (kq == 0) {
        float v = x2p[0] + x2p[1];
        #pragma unroll
        for (int off = 1; off < 64; off <<= 1) v += __shfl_xor(v, off);
        if (l == 0) atomicAdd(&x2acc[0], v * 0.25f);
    }
    __syncthreads();
    if (tid == 0 && kq == 0) atomicAdd(distsum, x2acc[0]);
}

// Pass 2: decode keys -> idx, counts, sum(s); gather quantized rows.
__global__ __launch_bounds__(256) void gather_p2(
    const unsigned long long* __restrict__ keys,
    const float* __restrict__ embed,
    float* __restrict__ out_q,
    float* __restrict__ out_idx,
    float* __restrict__ counts,
    float* __restrict__ distsum)
{
    __shared__ int   ibest[128];
    __shared__ float ssum[128];
    const int tid = threadIdx.x;
    const int n0  = blockIdx.x * 128;
    const int b   = n0 >> 11;          // TT = 2048
    const int t0  = n0 & 2047;

    if (tid < 128) {
        const unsigned long long key = keys[n0 + tid];
        const unsigned int idx = (unsigned int)(key & 0xFFFFFFFFull);
        unsigned int u = (unsigned int)(key >> 32);
        u = (u & 0x80000000u) ? (u ^ 0x80000000u) : ~u;   // inverse monotone map
        ibest[tid] = (int)idx;
        ssum[tid]  = __uint_as_float(u);                  // s = e^2 - 2 x.e
        out_idx[n0 + tid] = (float)idx;
        atomicAdd(&counts[idx], 1.0f);
    }
    __syncthreads();
    if (tid < 64) {
        float v = ssum[tid] + ssum[tid + 64];
        #pragma unroll
        for (int off = 1; off < 64; off <<= 1) v += __shfl_xor(v, off);
        if (tid == 0) atomicAdd(distsum, v);
    }
    // gather: out_q[b][j][t0+tt] = embed[ibest[tt]][j]  (embed L2-hot)
    #pragma unroll
    for (int p = 0; p < 32; ++p) {
        const int f  = p * 256 + tid;
        const int j  = f >> 7;
        const int tt = f & 127;
        out_q[(size_t)(b * DIM + j) * TT + t0 + tt] =
            embed[(size_t)ibest[tt] * DIM + j];
    }
}

// ======================= fallback path (Round-5, passed) ====================
#define EP_ROW   72
#define EP_PLANE 4608
#define SMEM_BYTES (36864 + 4096 + 512 + 512 + 16)

__global__ __launch_bounds__(256, 2) void argmin_fb(
    const float* __restrict__ x, const float* __restrict__ embed,
    float* __restrict__ out_q, float* __restrict__ out_idx,
    float* __restrict__ counts, float* __restrict__ distsum)
{
    __shared__ __align__(16) char smem[SMEM_BYTES];
    _Float16* ep  = (_Float16*)smem;
    float* e2s    = (float*)(smem + 36864);
    float* x2s    = (float*)(smem + 36864 + 4096);
    int*   ibest  = (int*)  (smem + 36864 + 4608);
    float* mdsum  = (float*)(smem + 36864 + 5120);

    const int tid = threadIdx.x;
    const int l   = tid & 63;
    const int w   = tid >> 6;
    const int q   = l >> 4;
    const int ln  = l & 15;
    const int bid = blockIdx.x;
    const int b   = bid >> 4;
    const int t0  = (bid & 15) << 7;

    if (tid == 0) mdsum[0] = 0.f;
    #pragma unroll
    for (int pass = 0; pass < 4; ++pass) {
        const int c = pass * 256 + tid;
        const float4* rp = (const float4*)(embed + (size_t)c * DIM);
        float s = 0.f;
        #pragma unroll
        for (int i = 0; i < 16; ++i) {
            const float4 v = rp[i];
            s += v.x * v.x + v.y * v.y + v.z * v.z + v.w * v.w;
        }
        e2s[c] = s;
    }
    f16x8 af[2][2][2];
    float x2p[2] = {0.f, 0.f};
    #pragma unroll
    for (int m = 0; m < 2; ++m)
        #pragma unroll
        for (int k = 0; k < 2; ++k)
            #pragma unroll
            for (int jj = 0; jj < 8; ++jj) {
                const int j = k * 32 + q * 8 + jj;
                const float xf = x[(size_t)(b * DIM + j) * TT + t0 + w * 32 + m * 16 + ln];
                const _Float16 h1 = (_Float16)xf;
                af[0][m][k][jj] = h1;
                af[1][m][k][jj] = (_Float16)(xf - (float)h1);
                x2p[m] = fmaf(xf, xf, x2p[m]);
            }
    #pragma unroll
    for (int m = 0; m < 2; ++m) {
        x2p[m] += __shfl_xor(x2p[m], 16);
        x2p[m] += __shfl_xor(x2p[m], 32);
    }
    if (q == 0) { x2s[w * 32 + ln] = x2p[0]; x2s[w * 32 + 16 + ln] = x2p[1]; }
    {
        #pragma unroll
        for (int pass = 0; pass < 4; ++pass) {
            const int c_loc = (tid >> 4) + pass * 16;
            const int j4    = (tid & 15) * 4;
            const float4 v = *(const float4*)(embed + (size_t)c_loc * DIM + j4);
            f16x4 h1, h2;
            h1[0] = (_Float16)v.x; h2[0] = (_Float16)(v.x - (float)h1[0]);
            h1[1] = (_Float16)v.y; h2[1] = (_Float16)(v.y - (float)h1[1]);
            h1[2] = (_Float16)v.z; h2[2] = (_Float16)(v.z - (float)h1[2]);
            h1[3] = (_Float16)v.w; h2[3] = (_Float16)(v.w - (float)h1[3]);
            *(f16x4*)(ep + c_loc * EP_ROW + j4)            = h1;
            *(f16x4*)(ep + EP_PLANE + c_loc * EP_ROW + j4) = h2;
        }
    }
    __syncthreads();
    float bs[2][4]; int bi[2][4];
    #pragma unroll
    for (int m = 0; m < 2; ++m)
        #pragma unroll
        for (int r = 0; r < 4; ++r) { bs[m][r] = FLT_MAX; bi[m][r] = 0; }
    for (int kc = 0; kc < 16; ++kc) {
        const int cur = kc & 1, nxt = cur ^ 1;
        float4 ev[4];
        if (kc < 15)
            #pragma unroll
            for (int pass = 0; pass < 4; ++pass) {
                const int c_loc = (tid >> 4) + pass * 16;
                const int j4    = (tid & 15) * 4;
                ev[pass] = *(const float4*)(embed + (size_t)((kc + 1) * 64 + c_loc) * DIM + j4);
            }
        const _Float16* p1 = ep + cur * 2 * EP_PLANE;
        const _Float16* p2 = p1 + EP_PLANE;
        #pragma unroll
        for (int n = 0; n < 4; ++n) {
            const int coff = (n * 16 + ln) * EP_ROW + q * 8;
            const f16x8 b1k0 = *(const f16x8*)(p1 + coff);
            const f16x8 b1k1 = *(const f16x8*)(p1 + coff + 32);
            const f16x8 b2k0 = *(const f16x8*)(p2 + coff);
            const f16x8 b2k1 = *(const f16x8*)(p2 + coff + 32);
            const int   c_lane = kc * 64 + n * 16 + ln;
            const float e2c    = e2s[c_lane];
            #pragma unroll
            for (int m = 0; m < 2; ++m) {
                f32x4 C = {0.f, 0.f, 0.f, 0.f};
                C = __builtin_amdgcn_mfma_f32_16x16x32_f16(af[1][m][0], b2k0, C, 0, 0, 0);
                C = __builtin_amdgcn_mfma_f32_16x16x32_f16(af[1][m][1], b2k1, C, 0, 0, 0);
                C = __builtin_amdgcn_mfma_f32_16x16x32_f16(af[1][m][0], b1k0, C, 0, 0, 0);
                C = __builtin_amdgcn_mfma_f32_16x16x32_f16(af[1][m][1], b1k1, C, 0, 0, 0);
                C = __builtin_amdgcn_mfma_f32_16x16x32_f16(af[0][m][0], b2k0, C, 0, 0, 0);
                C = __builtin_amdgcn_mfma_f32_16x16x32_f16(af[0][m][1], b2k1, C, 0, 0, 0);
                C = __builtin_amdgcn_mfma_f32_16x16x32_f16(af[0][m][0], b1k0, C, 0, 0, 0);
                C = __builtin_amdgcn_mfma_f32_16x16x32_f16(af[0][m][1], b1k1, C, 0, 0, 0);
                #pragma unroll
                for (int r = 0; r < 4; ++r) {
                    const float s = fmaf(-2.f, C[r], e2c);
                    if (s < bs[m][r]) { bs[m][r] = s; bi[m][r] = c_lane; }
                }
            }
        }
        if (kc < 15) {
            _Float16* w1 = ep + nxt * 2 * EP_PLANE;
            _Float16* w2 = w1 + EP_PLANE;
            #pragma unroll
            for (int pass = 0; pass < 4; ++pass) {
                const int c_loc = (tid >> 4) + pass * 16;
                const int j4    = (tid & 15) * 4;
                const float4 v = ev[pass];
                f16x4 h1, h2;
                h1[0] = (_Float16)v.x; h2[0] = (_Float16)(v.x - (float)h1[0]);
                h1[1] = (_Float16)v.y; h2[1] = (_Float16)(v.y - (float)h1[1]);
                h1[2] = (_Float16)v.z; h2[2] = (_Float16)(v.z - (float)h1[2]);
                h1[3] = (_Float16)v.w; h2[3] = (_Float16)(v.w - (float)h1[3]);
                *(f16x4*)(w1 + c_loc * EP_ROW + j4) = h1;
                *(f16x4*)(w2 + c_loc * EP_ROW + j4) = h2;
            }
        }
        __syncthreads();
    }
    float mdloc = 0.f;
    #pragma unroll
    for (int m = 0; m < 2; ++m)
        #pragma unroll
        for (int r = 0; r < 4; ++r) {
            float s = bs[m][r]; int i = bi[m][r];
            #pragma unroll
            for (int mask = 1; mask < 16; mask <<= 1) {
                const float s2 = __shfl_xor(s, mask);
                const int   i2 = __shfl_xor(i, mask);
                if (s2 < s || (s2 == s && i2 < i)) { s = s2; i = i2; }
            }
            if (ln == 0) {
                const int t_loc = w * 32 + m * 16 + q * 4 + r;
                ibest[t_loc] = i;
                out_idx[b * TT + t0 + t_loc] = (float)i;
                atomicAdd(&counts[i], 1.0f);
                mdloc += x2s[t_loc] + s;
            }
        }
    if (ln == 0) atomicAdd(mdsum, mdloc);
    __syncthreads();
    if (tid == 0) atomicAdd(distsum, mdsum[0]);
    #pragma unroll
    for (int p = 0; p < 32; ++p) {
        const int f  = p * 256 + tid;
        const int j  = f >> 7;
        const int tt = f & 127;
        out_q[(size_t)(b * DIM + j) * TT + t0 + tt] =
            embed[(size_t)ibest[tt] * DIM + j];
    }
}

// finalize: in-place counts->avg_probs, perplexity, usage, commitment
__global__ __launch_bounds__(1024) void finalize_kernel(
    float* __restrict__ avg, float* __restrict__ commit_slot,
    float* __restrict__ out_perp, float* __restrict__ out_usage)
{
    __shared__ float s_ent[1024];
    __shared__ float s_use[1024];
    const int k = threadIdx.x;
    const float p = avg[k] * (1.0f / (float)NTOT);
    avg[k] = p;
    s_ent[k] = p * logf(p + 1e-10f);
    s_use[k] = p * logf(p * 1024.f + 1e-10f);
    __syncthreads();
    for (int off = 512; off > 0; off >>= 1) {
        if (k < off) { s_ent[k] += s_ent[k + off]; s_use[k] += s_use[k + off]; }
        __syncthreads();
    }
    if (k == 0) {
        const float ds = commit_slot[0];
        *out_perp      = expf(-s_ent[0]);
        *out_usage     = s_use[0];
        commit_slot[0] = 0.25f * ds * (1.0f / ((float)NTOT * (float)DIM));
    }
}

extern "C" void kernel_launch(void* const* d_in, const int* in_sizes, int n_in,
                              void* d_out, int out_size, void* d_ws, size_t ws_size,
                              hipStream_t stream) {
    const float* x     = (const float*)d_in[0];
    const float* embed = (const float*)d_in[1];

    float* out        = (float*)d_out;
    float* out_q      = out;             // 4194304
    float* out_commit = out + 4194304;   // distsum accumulator first
    float* out_perp   = out + 4194305;
    float* out_avg    = out + 4194306;   // counts accumulator first
    float* out_idx    = out + 4195330;
    // usage at out + 4260866

    if (ws_size >= WS_NEED) {
        unsigned long long* keys = (unsigned long long*)d_ws;
        _Float16* planes = (_Float16*)((char*)d_ws + 524288);
        float*    e2g    = (float*)((char*)d_ws + 786432);
        prep_kernel<<<32, 256, 0, stream>>>(embed, planes, e2g, keys, out_avg, out_commit);
        argmin_p1<<<1024, 256, 0, stream>>>(x, (const f16x8*)planes, e2g, keys, out_commit);
        gather_p2<<<512, 256, 0, stream>>>(keys, embed, out_q, out_idx, out_avg, out_commit);
    } else {
        hipMemsetAsync(out_commit, 0, 1026 * sizeof(float), stream);
        argmin_fb<<<512, 256, 0, stream>>>(x, embed, out_q, out_idx, out_avg, out_commit);
    }
    finalize_kernel<<<1, 1024, 0, stream>>>(out_avg, out_commit, out_perp, out + 4260866);
}